// Round 5
// baseline (6363.362 us; speedup 1.0000x reference)
//
#include <hip/hip_runtime.h>
#include <stdint.h>

typedef float v4f __attribute__((ext_vector_type(4)));
typedef float v2f __attribute__((ext_vector_type(2)));

#define ROT(x, r) __builtin_rotateleft32((uint32_t)(x), (r))

// Threefry-2x32, 20 rounds
#define TF_G1(x0, x1) \
  x0 += x1; x1 = ROT(x1, 13); x1 ^= x0; \
  x0 += x1; x1 = ROT(x1, 15); x1 ^= x0; \
  x0 += x1; x1 = ROT(x1, 26); x1 ^= x0; \
  x0 += x1; x1 = ROT(x1, 6);  x1 ^= x0;

#define TF_G2(x0, x1) \
  x0 += x1; x1 = ROT(x1, 17); x1 ^= x0; \
  x0 += x1; x1 = ROT(x1, 29); x1 ^= x0; \
  x0 += x1; x1 = ROT(x1, 16); x1 ^= x0; \
  x0 += x1; x1 = ROT(x1, 24); x1 ^= x0;

__device__ __forceinline__ void threefry_full(uint32_t k0, uint32_t k1,
                                              uint32_t c0, uint32_t c1,
                                              uint32_t& o0, uint32_t& o1) {
  uint32_t ks2 = k0 ^ k1 ^ 0x1BD11BDAu;
  uint32_t x0 = c0 + k0, x1 = c1 + k1;
  TF_G1(x0, x1); x0 += k1;  x1 += ks2 + 1u;
  TF_G2(x0, x1); x0 += ks2; x1 += k0 + 2u;
  TF_G1(x0, x1); x0 += k0;  x1 += k1 + 3u;
  TF_G2(x0, x1); x0 += k1;  x1 += ks2 + 4u;
  TF_G1(x0, x1); x0 += ks2; x1 += k0 + 5u;
  o0 = x0; o1 = x1;
}

// scalar partitionable-mode draw (used for the jj=24 tail)
__device__ __forceinline__ uint32_t tf_bits(uint32_t k0, uint32_t k1, uint32_t ks2,
                                            uint32_t cnt) {
  uint32_t x0 = k0, x1 = cnt + k1;
  TF_G1(x0, x1); x0 += k1;  x1 += ks2 + 1u;
  TF_G2(x0, x1); x0 += ks2; x1 += k0 + 2u;
  TF_G1(x0, x1); x0 += k0;  x1 += k1 + 3u;
  TF_G2(x0, x1); x0 += k1;  x1 += ks2 + 4u;
  TF_G1(x0, x1); x0 += ks2; x1 += k0 + 5u;
  return x0 ^ x1;
}

// ---- 4-stream interleaved threefry: one sub-round across 4 states ----
#define SR4(r) \
  a0 += a1; a1 = ROT(a1, r); a1 ^= a0; \
  b0 += b1; b1 = ROT(b1, r); b1 ^= b0; \
  c0 += c1; c1 = ROT(c1, r); c1 ^= c0; \
  d0 += d1; d1 = ROT(d1, r); d1 ^= d0;

#define INJ4(p, q) \
  a0 += (p); a1 += (q); \
  b0 += (p); b1 += (q); \
  c0 += (p); c1 += (q); \
  d0 += (p); d1 += (q);

__device__ __forceinline__ void tf_bits4(uint32_t k0, uint32_t k1, uint32_t ks2,
                                         uint32_t ca, uint32_t cb, uint32_t cc,
                                         uint32_t cd, uint32_t& ra, uint32_t& rb,
                                         uint32_t& rc, uint32_t& rd) {
  uint32_t a0 = k0, a1 = ca + k1;
  uint32_t b0 = k0, b1 = cb + k1;
  uint32_t c0 = k0, c1 = cc + k1;
  uint32_t d0 = k0, d1 = cd + k1;
  SR4(13) SR4(15) SR4(26) SR4(6)
  INJ4(k1, ks2 + 1u)
  SR4(17) SR4(29) SR4(16) SR4(24)
  INJ4(ks2, k0 + 2u)
  SR4(13) SR4(15) SR4(26) SR4(6)
  INJ4(k0, k1 + 3u)
  SR4(17) SR4(29) SR4(16) SR4(24)
  INJ4(k1, ks2 + 4u)
  SR4(13) SR4(15) SR4(26) SR4(6)
  INJ4(ks2, k0 + 5u)
  ra = a0 ^ a1; rb = b0 ^ b1; rc = c0 ^ c1; rd = d0 ^ d1;
}

// 32-lane butterfly reduce (same order as rounds 1/3/4: absmax 0.0)
__device__ __forceinline__ v2f bfly(v2f r) {
#pragma unroll
  for (int m = 1; m < 32; m <<= 1) {
    v2f q;
    q.x = __shfl_xor(r.x, m, 32);
    q.y = __shfl_xor(r.y, m, 32);
    r += q;
  }
  return r;
}

__device__ __forceinline__ void lif2(v2f I, v2f& V, v2f& A) {
  v2f vv = V + (I - V) * 0.5f;
  float sx = (vv.x >= 1.0f) ? 1.0f : 0.0f;
  float sy = (vv.y >= 1.0f) ? 1.0f : 0.0f;
  A.x += sx; A.y += sy;
  V.x = (1.0f - sx) * vv.x;
  V.y = (1.0f - sy) * vv.y;
}

// xig[row][c] = (floor(x*2^23) << 9) for c<784, else 0 (pad lanes never spike)
__global__ __launch_bounds__(256)
void prep_xi(const float* __restrict__ x, uint32_t* __restrict__ xig) {
  int i = blockIdx.x * 256 + threadIdx.x;
  if (i >= 16384 * 800) return;
  int row = i / 800;
  int c = i - row * 800;
  uint32_t t = 0u;
  if (c < 784) {
    float xv = x[row * 784 + c];
    t = ((uint32_t)(xv * 8388608.0f)) << 9;    // exact: x = k*2^-23, k < 2^23
  }
  xig[i] = t;
}

// 16384 rows, 784 features, 10 outputs, 100 timesteps
// block: 256 threads = 8 rows x 32 lanes; grid 2048; 4 blocks/CU
template <bool USE_XIG>
__global__ __launch_bounds__(256, 4)
void snn_lif_kernel(const float* __restrict__ x, const uint32_t* __restrict__ xig,
                    const float* __restrict__ W, float* __restrict__ out) {
  // Wp[jj][q][jl][4]: q-th float4 of W[:, j=jl+32*jj]  (o = 4q+c; pads = 0)
  __shared__ __align__(16) float Wp[25 * 3 * 32 * 4];
  __shared__ uint32_t keys[100][2];

  const int tid = threadIdx.x;

  for (int s = tid; s < 25 * 3 * 32 * 4; s += 256) {
    int c = s & 3;
    int jl = (s >> 2) & 31;
    int rest = s >> 7;
    int q = rest % 3;
    int jj = rest / 3;
    int o = q * 4 + c;
    int j = jl + 32 * jj;
    float w = 0.0f;
    if (o < 10 && j < 784) w = W[o * 784 + j];
    Wp[s] = w;
  }
  if (tid < 100) {
    threefry_full(0u, 42u, 0u, (uint32_t)tid, keys[tid][0], keys[tid][1]);
  }
  __syncthreads();

  const int row = blockIdx.x * 8 + (tid >> 5);
  const int hl = tid & 31;
  const uint32_t cntbase = (uint32_t)row * 784u + (uint32_t)hl;

  const uint32_t* xrow_i = xig + (size_t)row * 800 + hl;
  const float* xrow = x + (size_t)row * 784;

  v2f V0 = {0, 0}, V1 = {0, 0}, V2 = {0, 0}, V3 = {0, 0}, V4 = {0, 0};
  v2f A0 = {0, 0}, A1 = {0, 0}, A2 = {0, 0}, A3 = {0, 0}, A4 = {0, 0};

  const v4f* wq = (const v4f*)&Wp[(size_t)hl * 4];

  for (int t = 0; t < 100; ++t) {
    const uint32_t k0 = __builtin_amdgcn_readfirstlane(keys[t][0]);
    const uint32_t k1 = __builtin_amdgcn_readfirstlane(keys[t][1]);
    const uint32_t ks2 = k0 ^ k1 ^ 0x1BD11BDAu;

    v2f I0 = {0, 0}, I1 = {0, 0}, I2 = {0, 0}, I3 = {0, 0}, I4 = {0, 0};

    // FMA application, jj-ascending, identical expression order to round 4
#define ACC_FMA(jj, s)                              \
    {                                               \
      const v2f s2 = {(s), (s)};                    \
      const v4f wa = wq[(jj) * 96];                 \
      const v4f wb = wq[(jj) * 96 + 32];            \
      const v4f wc = wq[(jj) * 96 + 64];            \
      I0 += s2 * wa.lo;                             \
      I1 += s2 * wa.hi;                             \
      I2 += s2 * wb.lo;                             \
      I3 += s2 * wb.hi;                             \
      I4 += s2 * wc.lo;                             \
    }

    if (USE_XIG) {
      // 6 quad-groups: 4-way interleaved ciphers, thresholds prefetched
#pragma unroll
      for (int q = 0; q < 6; ++q) {
        const int jj = q * 4;
        const uint32_t ta = xrow_i[jj * 32];
        const uint32_t tb = xrow_i[(jj + 1) * 32];
        const uint32_t tc = xrow_i[(jj + 2) * 32];
        const uint32_t td = xrow_i[(jj + 3) * 32];
        uint32_t ba, bb, bc, bd;
        tf_bits4(k0, k1, ks2,
                 cntbase + (uint32_t)(jj * 32),
                 cntbase + (uint32_t)((jj + 1) * 32),
                 cntbase + (uint32_t)((jj + 2) * 32),
                 cntbase + (uint32_t)((jj + 3) * 32),
                 ba, bb, bc, bd);
        const float sa = (ba < ta) ? 1.0f : 0.0f;
        const float sb = (bb < tb) ? 1.0f : 0.0f;
        const float sc = (bc < tc) ? 1.0f : 0.0f;
        const float sd = (bd < td) ? 1.0f : 0.0f;
        ACC_FMA(jj + 0, sa)
        ACC_FMA(jj + 1, sb)
        ACC_FMA(jj + 2, sc)
        ACC_FMA(jj + 3, sd)
      }
      // jj = 24 tail
      {
        const uint32_t thr = xrow_i[24 * 32];
        const uint32_t bits = tf_bits(k0, k1, ks2, cntbase + 24u * 32u);
        const float s = (bits < thr) ? 1.0f : 0.0f;
        ACC_FMA(24, s)
      }
    } else {
      // fallback: round-4 scalar path computing thresholds from x inline
#pragma unroll 5
      for (int jj = 0; jj < 25; ++jj) {
        const uint32_t bits = tf_bits(k0, k1, ks2, cntbase + (uint32_t)(jj * 32));
        int j = hl + jj * 32;
        float xv = xrow[(j < 784) ? j : 783];
        uint32_t k = (uint32_t)(xv * 8388608.0f);
        uint32_t thr = (j < 784) ? (k << 9) : 0u;
        const float s = (bits < thr) ? 1.0f : 0.0f;
        ACC_FMA(jj, s)
      }
    }
#undef ACC_FMA

    I0 = bfly(I0); I1 = bfly(I1); I2 = bfly(I2); I3 = bfly(I3); I4 = bfly(I4);

    lif2(I0, V0, A0);
    lif2(I1, V1, A1);
    lif2(I2, V2, A2);
    lif2(I3, V3, A3);
    lif2(I4, V4, A4);
  }

  if (hl == 0) {
    float* orow = out + (size_t)row * 10;
    orow[0] = A0.x / 100.0f; orow[1] = A0.y / 100.0f;
    orow[2] = A1.x / 100.0f; orow[3] = A1.y / 100.0f;
    orow[4] = A2.x / 100.0f; orow[5] = A2.y / 100.0f;
    orow[6] = A3.x / 100.0f; orow[7] = A3.y / 100.0f;
    orow[8] = A4.x / 100.0f; orow[9] = A4.y / 100.0f;
  }
}

extern "C" void kernel_launch(void* const* d_in, const int* in_sizes, int n_in,
                              void* d_out, int out_size, void* d_ws, size_t ws_size,
                              hipStream_t stream) {
  const float* x = (const float*)d_in[0];   // [16384,1,28,28] fp32
  const float* W = (const float*)d_in[1];   // [10,784] fp32
  float* out = (float*)d_out;               // [16384,10] fp32

  const size_t need = (size_t)16384 * 800 * 4;   // 52.4 MB threshold table
  if (ws_size >= need) {
    uint32_t* xig = (uint32_t*)d_ws;
    hipLaunchKernelGGL(prep_xi, dim3((16384 * 800 + 255) / 256), dim3(256), 0,
                       stream, x, xig);
    hipLaunchKernelGGL((snn_lif_kernel<true>), dim3(2048), dim3(256), 0, stream,
                       x, xig, W, out);
  } else {
    hipLaunchKernelGGL((snn_lif_kernel<false>), dim3(2048), dim3(256), 0, stream,
                       x, (const uint32_t*)nullptr, W, out);
  }
}

// Round 6
// 3229.655 us; speedup vs baseline: 1.9703x; 1.9703x over previous
//
#include <hip/hip_runtime.h>
#include <stdint.h>

#define ROT(x, r) __builtin_rotateleft32((uint32_t)(x), (r))

// Threefry-2x32, 20 rounds
#define TF_G1(x0, x1) \
  x0 += x1; x1 = ROT(x1, 13); x1 ^= x0; \
  x0 += x1; x1 = ROT(x1, 15); x1 ^= x0; \
  x0 += x1; x1 = ROT(x1, 26); x1 ^= x0; \
  x0 += x1; x1 = ROT(x1, 6);  x1 ^= x0;

#define TF_G2(x0, x1) \
  x0 += x1; x1 = ROT(x1, 17); x1 ^= x0; \
  x0 += x1; x1 = ROT(x1, 29); x1 ^= x0; \
  x0 += x1; x1 = ROT(x1, 16); x1 ^= x0; \
  x0 += x1; x1 = ROT(x1, 24); x1 ^= x0;

__device__ __forceinline__ void threefry_full(uint32_t k0, uint32_t k1,
                                              uint32_t c0, uint32_t c1,
                                              uint32_t& o0, uint32_t& o1) {
  uint32_t ks2 = k0 ^ k1 ^ 0x1BD11BDAu;
  uint32_t x0 = c0 + k0, x1 = c1 + k1;
  TF_G1(x0, x1); x0 += k1;  x1 += ks2 + 1u;
  TF_G2(x0, x1); x0 += ks2; x1 += k0 + 2u;
  TF_G1(x0, x1); x0 += k0;  x1 += k1 + 3u;
  TF_G2(x0, x1); x0 += k1;  x1 += ks2 + 4u;
  TF_G1(x0, x1); x0 += ks2; x1 += k0 + 5u;
  o0 = x0; o1 = x1;
}

__device__ __forceinline__ uint32_t tf_bits(uint32_t k0, uint32_t k1, uint32_t ks2,
                                            uint32_t cnt) {
  uint32_t x0 = k0, x1 = cnt + k1;
  TF_G1(x0, x1); x0 += k1;  x1 += ks2 + 1u;
  TF_G2(x0, x1); x0 += ks2; x1 += k0 + 2u;
  TF_G1(x0, x1); x0 += k0;  x1 += k1 + 3u;
  TF_G2(x0, x1); x0 += k1;  x1 += ks2 + 4u;
  TF_G1(x0, x1); x0 += ks2; x1 += k0 + 5u;
  return x0 ^ x1;
}

// ---- 4-stream interleaved threefry ----
#define SR4(r) \
  a0 += a1; a1 = ROT(a1, r); a1 ^= a0; \
  b0 += b1; b1 = ROT(b1, r); b1 ^= b0; \
  c0 += c1; c1 = ROT(c1, r); c1 ^= c0; \
  d0 += d1; d1 = ROT(d1, r); d1 ^= d0;

#define INJ4(p, q) \
  a0 += (p); a1 += (q); \
  b0 += (p); b1 += (q); \
  c0 += (p); c1 += (q); \
  d0 += (p); d1 += (q);

__device__ __forceinline__ void tf_bits4(uint32_t k0, uint32_t k1, uint32_t ks2,
                                         uint32_t ca, uint32_t cb, uint32_t cc,
                                         uint32_t cd, uint32_t& ra, uint32_t& rb,
                                         uint32_t& rc, uint32_t& rd) {
  uint32_t a0 = k0, a1 = ca + k1;
  uint32_t b0 = k0, b1 = cb + k1;
  uint32_t c0 = k0, c1 = cc + k1;
  uint32_t d0 = k0, d1 = cd + k1;
  SR4(13) SR4(15) SR4(26) SR4(6)
  INJ4(k1, ks2 + 1u)
  SR4(17) SR4(29) SR4(16) SR4(24)
  INJ4(ks2, k0 + 2u)
  SR4(13) SR4(15) SR4(26) SR4(6)
  INJ4(k0, k1 + 3u)
  SR4(17) SR4(29) SR4(16) SR4(24)
  INJ4(k1, ks2 + 4u)
  SR4(13) SR4(15) SR4(26) SR4(6)
  INJ4(ks2, k0 + 5u)
  ra = a0 ^ a1; rb = b0 ^ b1; rc = c0 ^ c1; rd = d0 ^ d1;
}

// ---------- phase 1: one thread = one (row,t); I[row,t,0..9] -> ws ----------
// j loop is wave-uniform: x-threshold loads are same-address broadcasts
// (lanes share the row), W reads are same-address LDS broadcasts.
__global__ __launch_bounds__(256, 2)
void snn_phase1(const float* __restrict__ x, const float* __restrict__ W,
                float* __restrict__ Iws) {
  __shared__ __align__(16) float Wl[784 * 12];   // Wl[j][o], o padded to 12
  __shared__ uint32_t keys[100][2];

  const int tid = threadIdx.x;

  for (int j = tid; j < 784; j += 256) {
#pragma unroll
    for (int o = 0; o < 10; ++o) Wl[j * 12 + o] = W[o * 784 + j];
    Wl[j * 12 + 10] = 0.0f;
    Wl[j * 12 + 11] = 0.0f;
  }
  if (tid < 100) {
    threefry_full(0u, 42u, 0u, (uint32_t)tid, keys[tid][0], keys[tid][1]);
  }
  __syncthreads();

  const uint32_t task = blockIdx.x * 256u + (uint32_t)tid;   // < 1,638,400
  const uint32_t row = task / 100u;
  const uint32_t t = task - row * 100u;
  const uint32_t k0 = keys[t][0];
  const uint32_t k1 = keys[t][1];
  const uint32_t ks2 = k0 ^ k1 ^ 0x1BD11BDAu;
  const uint32_t cnt0 = row * 784u;
  const float* xrow = x + cnt0;                  // 16B-aligned (3136B stride)

  float I0 = 0, I1 = 0, I2 = 0, I3 = 0, I4 = 0,
        I5 = 0, I6 = 0, I7 = 0, I8 = 0, I9 = 0;

  // j ascending 0..783 — summation order identical to round 2 (absmax 0.0107)
#define APPLY(jq, s)                              \
  {                                               \
    const float4 wA = *(const float4*)&Wl[(jq) * 12];     \
    const float4 wB = *(const float4*)&Wl[(jq) * 12 + 4]; \
    const float2 wC = *(const float2*)&Wl[(jq) * 12 + 8]; \
    I0 += (s) * wA.x; I1 += (s) * wA.y; I2 += (s) * wA.z; I3 += (s) * wA.w; \
    I4 += (s) * wB.x; I5 += (s) * wB.y; I6 += (s) * wB.z; I7 += (s) * wB.w; \
    I8 += (s) * wC.x; I9 += (s) * wC.y;           \
  }

  for (uint32_t j = 0; j < 784u; j += 4u) {
    const float4 xv = *(const float4*)(xrow + j);          // wave-broadcast
    // thr = floor(x*2^23)<<9 ; bits<thr == (u<x) bit-exactly
    const uint32_t ta = ((uint32_t)(xv.x * 8388608.0f)) << 9;
    const uint32_t tb = ((uint32_t)(xv.y * 8388608.0f)) << 9;
    const uint32_t tc = ((uint32_t)(xv.z * 8388608.0f)) << 9;
    const uint32_t td = ((uint32_t)(xv.w * 8388608.0f)) << 9;
    uint32_t ba, bb, bc, bd;
    tf_bits4(k0, k1, ks2, cnt0 + j, cnt0 + j + 1u, cnt0 + j + 2u, cnt0 + j + 3u,
             ba, bb, bc, bd);
    const float sa = (ba < ta) ? 1.0f : 0.0f;
    const float sb = (bb < tb) ? 1.0f : 0.0f;
    const float sc = (bc < tc) ? 1.0f : 0.0f;
    const float sd = (bd < td) ? 1.0f : 0.0f;
    APPLY(j + 0u, sa)
    APPLY(j + 1u, sb)
    APPLY(j + 2u, sc)
    APPLY(j + 3u, sd)
  }
#undef APPLY

  // store 10 floats at task*10 (8B-aligned records)
  float* dst = Iws + (size_t)task * 10;
  ((float2*)dst)[0] = make_float2(I0, I1);
  ((float2*)dst)[1] = make_float2(I2, I3);
  ((float2*)dst)[2] = make_float2(I4, I5);
  ((float2*)dst)[3] = make_float2(I6, I7);
  ((float2*)dst)[4] = make_float2(I8, I9);
}

// ---------- phase 3: one thread = one (row,o); LIF scan over t ----------
__global__ __launch_bounds__(256)
void snn_phase3(const float* __restrict__ Iws, float* __restrict__ out) {
  const uint32_t id = blockIdx.x * 256u + threadIdx.x;   // < 163,840
  const uint32_t row = id / 10u;
  const uint32_t o = id - row * 10u;
  const float* Ip = Iws + (size_t)row * 1000 + o;
  float v = 0.0f, acc = 0.0f;
  for (int t = 0; t < 100; ++t) {
    const float I = Ip[t * 10];
    const float vv = v + (I - v) * 0.5f;          // exact (x0.5)
    const float s = (vv >= 1.0f) ? 1.0f : 0.0f;
    acc += s;
    v = (1.0f - s) * vv;                          // hard reset
  }
  out[id] = acc / 100.0f;
}

// ---------- fallback (round-4 structure, inline thresholds) ----------
__global__ __launch_bounds__(256, 4)
void snn_fallback(const float* __restrict__ x, const float* __restrict__ W,
                  float* __restrict__ out) {
  __shared__ __align__(16) float Wp[25 * 3 * 32 * 4];
  __shared__ uint32_t keys[100][2];
  const int tid = threadIdx.x;
  for (int s = tid; s < 25 * 3 * 32 * 4; s += 256) {
    int c = s & 3, jl = (s >> 2) & 31, rest = s >> 7;
    int q = rest % 3, jj = rest / 3;
    int o = q * 4 + c, j = jl + 32 * jj;
    float w = 0.0f;
    if (o < 10 && j < 784) w = W[o * 784 + j];
    Wp[s] = w;
  }
  if (tid < 100)
    threefry_full(0u, 42u, 0u, (uint32_t)tid, keys[tid][0], keys[tid][1]);
  __syncthreads();

  const int row = blockIdx.x * 8 + (tid >> 5);
  const int hl = tid & 31;
  const uint32_t cntbase = (uint32_t)row * 784u + (uint32_t)hl;
  const float* xrow = x + (size_t)row * 784;
  float v[10], acc[10];
#pragma unroll
  for (int o = 0; o < 10; ++o) { v[o] = 0.0f; acc[o] = 0.0f; }
  const float4* wq = (const float4*)&Wp[(size_t)hl * 4];

  for (int t = 0; t < 100; ++t) {
    uint32_t k0 = __builtin_amdgcn_readfirstlane(keys[t][0]);
    uint32_t k1 = __builtin_amdgcn_readfirstlane(keys[t][1]);
    uint32_t ks2 = k0 ^ k1 ^ 0x1BD11BDAu;
    float I[10];
#pragma unroll
    for (int o = 0; o < 10; ++o) I[o] = 0.0f;
#pragma unroll 5
    for (int jj = 0; jj < 25; ++jj) {
      const uint32_t bits = tf_bits(k0, k1, ks2, cntbase + (uint32_t)(jj * 32));
      int j = hl + jj * 32;
      float xv = xrow[(j < 784) ? j : 783];
      uint32_t k = (uint32_t)(xv * 8388608.0f);
      uint32_t thr = (j < 784) ? (k << 9) : 0u;
      const float s = (bits < thr) ? 1.0f : 0.0f;
      const float4 wa = wq[jj * 96];
      const float4 wb = wq[jj * 96 + 32];
      const float4 wc = wq[jj * 96 + 64];
      I[0] += s * wa.x; I[1] += s * wa.y; I[2] += s * wa.z; I[3] += s * wa.w;
      I[4] += s * wb.x; I[5] += s * wb.y; I[6] += s * wb.z; I[7] += s * wb.w;
      I[8] += s * wc.x; I[9] += s * wc.y;
    }
#pragma unroll
    for (int o = 0; o < 10; ++o) {
      float r = I[o];
#pragma unroll
      for (int m = 1; m < 32; m <<= 1) r += __shfl_xor(r, m, 32);
      I[o] = r;
    }
#pragma unroll
    for (int o = 0; o < 10; ++o) {
      float vv = v[o] + (I[o] - v[o]) * 0.5f;
      float s = (vv >= 1.0f) ? 1.0f : 0.0f;
      acc[o] += s;
      v[o] = (1.0f - s) * vv;
    }
  }
  if (hl == 0) {
#pragma unroll
    for (int o = 0; o < 10; ++o)
      out[(size_t)row * 10 + o] = acc[o] / 100.0f;
  }
}

extern "C" void kernel_launch(void* const* d_in, const int* in_sizes, int n_in,
                              void* d_out, int out_size, void* d_ws, size_t ws_size,
                              hipStream_t stream) {
  const float* x = (const float*)d_in[0];   // [16384,1,28,28] fp32
  const float* W = (const float*)d_in[1];   // [10,784] fp32
  float* out = (float*)d_out;               // [16384,10] fp32

  const size_t need = (size_t)16384 * 100 * 10 * sizeof(float);   // 65.5 MB
  if (ws_size >= need) {
    float* Iws = (float*)d_ws;
    hipLaunchKernelGGL(snn_phase1, dim3(6400), dim3(256), 0, stream, x, W, Iws);
    hipLaunchKernelGGL(snn_phase3, dim3(640), dim3(256), 0, stream, Iws, out);
  } else {
    hipLaunchKernelGGL(snn_fallback, dim3(2048), dim3(256), 0, stream, x, W, out);
  }
}

// Round 7
// 3208.348 us; speedup vs baseline: 1.9834x; 1.0066x over previous
//
#include <hip/hip_runtime.h>
#include <stdint.h>

typedef float v4f __attribute__((ext_vector_type(4)));
typedef float v2f __attribute__((ext_vector_type(2)));

#define ROT(x, r) __builtin_rotateleft32((uint32_t)(x), (r))

// Threefry-2x32, 20 rounds
#define TF_G1(x0, x1) \
  x0 += x1; x1 = ROT(x1, 13); x1 ^= x0; \
  x0 += x1; x1 = ROT(x1, 15); x1 ^= x0; \
  x0 += x1; x1 = ROT(x1, 26); x1 ^= x0; \
  x0 += x1; x1 = ROT(x1, 6);  x1 ^= x0;

#define TF_G2(x0, x1) \
  x0 += x1; x1 = ROT(x1, 17); x1 ^= x0; \
  x0 += x1; x1 = ROT(x1, 29); x1 ^= x0; \
  x0 += x1; x1 = ROT(x1, 16); x1 ^= x0; \
  x0 += x1; x1 = ROT(x1, 24); x1 ^= x0;

__device__ __forceinline__ void threefry_full(uint32_t k0, uint32_t k1,
                                              uint32_t c0, uint32_t c1,
                                              uint32_t& o0, uint32_t& o1) {
  uint32_t ks2 = k0 ^ k1 ^ 0x1BD11BDAu;
  uint32_t x0 = c0 + k0, x1 = c1 + k1;
  TF_G1(x0, x1); x0 += k1;  x1 += ks2 + 1u;
  TF_G2(x0, x1); x0 += ks2; x1 += k0 + 2u;
  TF_G1(x0, x1); x0 += k0;  x1 += k1 + 3u;
  TF_G2(x0, x1); x0 += k1;  x1 += ks2 + 4u;
  TF_G1(x0, x1); x0 += ks2; x1 += k0 + 5u;
  o0 = x0; o1 = x1;
}

__device__ __forceinline__ uint32_t tf_bits(uint32_t k0, uint32_t k1, uint32_t ks2,
                                            uint32_t cnt) {
  uint32_t x0 = k0, x1 = cnt + k1;
  TF_G1(x0, x1); x0 += k1;  x1 += ks2 + 1u;
  TF_G2(x0, x1); x0 += ks2; x1 += k0 + 2u;
  TF_G1(x0, x1); x0 += k0;  x1 += k1 + 3u;
  TF_G2(x0, x1); x0 += k1;  x1 += ks2 + 4u;
  TF_G1(x0, x1); x0 += ks2; x1 += k0 + 5u;
  return x0 ^ x1;
}

// ---- 4-stream interleaved threefry ----
#define SR4(r) \
  a0 += a1; a1 = ROT(a1, r); a1 ^= a0; \
  b0 += b1; b1 = ROT(b1, r); b1 ^= b0; \
  c0 += c1; c1 = ROT(c1, r); c1 ^= c0; \
  d0 += d1; d1 = ROT(d1, r); d1 ^= d0;

#define INJ4(p, q) \
  a0 += (p); a1 += (q); \
  b0 += (p); b1 += (q); \
  c0 += (p); c1 += (q); \
  d0 += (p); d1 += (q);

__device__ __forceinline__ void tf_bits4(uint32_t k0, uint32_t k1, uint32_t ks2,
                                         uint32_t ca, uint32_t cb, uint32_t cc,
                                         uint32_t cd, uint32_t& ra, uint32_t& rb,
                                         uint32_t& rc, uint32_t& rd) {
  uint32_t a0 = k0, a1 = ca + k1;
  uint32_t b0 = k0, b1 = cb + k1;
  uint32_t c0 = k0, c1 = cc + k1;
  uint32_t d0 = k0, d1 = cd + k1;
  SR4(13) SR4(15) SR4(26) SR4(6)
  INJ4(k1, ks2 + 1u)
  SR4(17) SR4(29) SR4(16) SR4(24)
  INJ4(ks2, k0 + 2u)
  SR4(13) SR4(15) SR4(26) SR4(6)
  INJ4(k0, k1 + 3u)
  SR4(17) SR4(29) SR4(16) SR4(24)
  INJ4(k1, ks2 + 4u)
  SR4(13) SR4(15) SR4(26) SR4(6)
  INJ4(ks2, k0 + 5u)
  ra = a0 ^ a1; rb = b0 ^ b1; rc = c0 ^ c1; rd = d0 ^ d1;
}

// thr[row*784+j] = floor(x*2^23)<<9 ;  bits < thr  ==  (u < x) bit-exactly
__global__ __launch_bounds__(256)
void prep_thr(const float* __restrict__ x, uint32_t* __restrict__ thr) {
  int i = blockIdx.x * 256 + threadIdx.x;
  if (i >= 16384 * 784) return;
  thr[i] = ((uint32_t)(x[i] * 8388608.0f)) << 9;   // exact: x = m*2^-23
}

// ---------- phase 1: one thread = one (row,t); I[row,t,0..9] -> ws ----------
// j loop wave-uniform; W reads are same-address LDS broadcasts.
// Loads are issued BEFORE the 292-op cipher of the same group -> latency hidden.
template <bool USE_THR>
__global__ __launch_bounds__(256, 4)
void snn_phase1(const float* __restrict__ x, const uint32_t* __restrict__ thrg,
                const float* __restrict__ W, float* __restrict__ Iws) {
  __shared__ __align__(16) float Wl[784 * 12];   // Wl[j][o], o padded to 12
  __shared__ uint32_t keys[100][2];

  const int tid = threadIdx.x;

  for (int j = tid; j < 784; j += 256) {
#pragma unroll
    for (int o = 0; o < 10; ++o) Wl[j * 12 + o] = W[o * 784 + j];
    Wl[j * 12 + 10] = 0.0f;
    Wl[j * 12 + 11] = 0.0f;
  }
  if (tid < 100) {
    threefry_full(0u, 42u, 0u, (uint32_t)tid, keys[tid][0], keys[tid][1]);
  }
  __syncthreads();

  const uint32_t task = blockIdx.x * 256u + (uint32_t)tid;   // < 1,638,400
  const uint32_t row = task / 100u;
  const uint32_t t = task - row * 100u;
  const uint32_t k0 = keys[t][0];
  const uint32_t k1 = keys[t][1];
  const uint32_t ks2 = k0 ^ k1 ^ 0x1BD11BDAu;
  const uint32_t cnt0 = row * 784u;

  const uint32_t* trow = thrg + cnt0;            // 16B-aligned (3136B stride)
  const float* xrow = x + cnt0;

  v2f I01 = {0, 0}, I23 = {0, 0}, I45 = {0, 0}, I67 = {0, 0}, I89 = {0, 0};

  // current-group thresholds, software-pipelined one group ahead
  uint4 tv;
  if (USE_THR) {
    tv = *(const uint4*)trow;
  } else {
    const float4 xv = *(const float4*)xrow;
    tv.x = ((uint32_t)(xv.x * 8388608.0f)) << 9;
    tv.y = ((uint32_t)(xv.y * 8388608.0f)) << 9;
    tv.z = ((uint32_t)(xv.z * 8388608.0f)) << 9;
    tv.w = ((uint32_t)(xv.w * 8388608.0f)) << 9;
  }

  for (uint32_t j = 0; j < 784u; j += 4u) {
    // ---- prefetch next group's thresholds (completes during this cipher) ----
    uint4 tv_next = tv;
    if (j + 4u < 784u) {
      if (USE_THR) {
        tv_next = *(const uint4*)(trow + j + 4u);
      } else {
        const float4 xv = *(const float4*)(xrow + j + 4u);
        tv_next.x = ((uint32_t)(xv.x * 8388608.0f)) << 9;
        tv_next.y = ((uint32_t)(xv.y * 8388608.0f)) << 9;
        tv_next.z = ((uint32_t)(xv.z * 8388608.0f)) << 9;
        tv_next.w = ((uint32_t)(xv.w * 8388608.0f)) << 9;
      }
    }

    // ---- W loads for THIS group, issued before the cipher ----
    const v4f wA0 = *(const v4f*)&Wl[(j + 0) * 12];
    const v4f wB0 = *(const v4f*)&Wl[(j + 0) * 12 + 4];
    const v2f wC0 = *(const v2f*)&Wl[(j + 0) * 12 + 8];
    const v4f wA1 = *(const v4f*)&Wl[(j + 1) * 12];
    const v4f wB1 = *(const v4f*)&Wl[(j + 1) * 12 + 4];
    const v2f wC1 = *(const v2f*)&Wl[(j + 1) * 12 + 8];
    const v4f wA2 = *(const v4f*)&Wl[(j + 2) * 12];
    const v4f wB2 = *(const v4f*)&Wl[(j + 2) * 12 + 4];
    const v2f wC2 = *(const v2f*)&Wl[(j + 2) * 12 + 8];
    const v4f wA3 = *(const v4f*)&Wl[(j + 3) * 12];
    const v4f wB3 = *(const v4f*)&Wl[(j + 3) * 12 + 4];
    const v2f wC3 = *(const v2f*)&Wl[(j + 3) * 12 + 8];

    // ---- cipher (292 VALU ops: covers the load latency above) ----
    uint32_t ba, bb, bc, bd;
    tf_bits4(k0, k1, ks2, cnt0 + j, cnt0 + j + 1u, cnt0 + j + 2u, cnt0 + j + 3u,
             ba, bb, bc, bd);

    // ---- compare + packed FMA, order identical to round 6 componentwise ----
    const float sa = (ba < tv.x) ? 1.0f : 0.0f;
    const float sb = (bb < tv.y) ? 1.0f : 0.0f;
    const float sc = (bc < tv.z) ? 1.0f : 0.0f;
    const float sd = (bd < tv.w) ? 1.0f : 0.0f;
    const v2f sa2 = {sa, sa}, sb2 = {sb, sb}, sc2 = {sc, sc}, sd2 = {sd, sd};

    I01 += sa2 * wA0.lo; I23 += sa2 * wA0.hi; I45 += sa2 * wB0.lo;
    I67 += sa2 * wB0.hi; I89 += sa2 * wC0;
    I01 += sb2 * wA1.lo; I23 += sb2 * wA1.hi; I45 += sb2 * wB1.lo;
    I67 += sb2 * wB1.hi; I89 += sb2 * wC1;
    I01 += sc2 * wA2.lo; I23 += sc2 * wA2.hi; I45 += sc2 * wB2.lo;
    I67 += sc2 * wB2.hi; I89 += sc2 * wC2;
    I01 += sd2 * wA3.lo; I23 += sd2 * wA3.hi; I45 += sd2 * wB3.lo;
    I67 += sd2 * wB3.hi; I89 += sd2 * wC3;

    tv = tv_next;
  }

  float* dst = Iws + (size_t)task * 10;
  ((float2*)dst)[0] = make_float2(I01.x, I01.y);
  ((float2*)dst)[1] = make_float2(I23.x, I23.y);
  ((float2*)dst)[2] = make_float2(I45.x, I45.y);
  ((float2*)dst)[3] = make_float2(I67.x, I67.y);
  ((float2*)dst)[4] = make_float2(I89.x, I89.y);
}

// ---------- phase 3: one thread = one (row,o); LIF scan over t ----------
__global__ __launch_bounds__(256)
void snn_phase3(const float* __restrict__ Iws, float* __restrict__ out) {
  const uint32_t id = blockIdx.x * 256u + threadIdx.x;   // < 163,840
  const uint32_t row = id / 10u;
  const uint32_t o = id - row * 10u;
  const float* Ip = Iws + (size_t)row * 1000 + o;
  float v = 0.0f, acc = 0.0f;
  for (int t = 0; t < 100; ++t) {
    const float I = Ip[t * 10];
    const float vv = v + (I - v) * 0.5f;          // exact (x0.5)
    const float s = (vv >= 1.0f) ? 1.0f : 0.0f;
    acc += s;
    v = (1.0f - s) * vv;                          // hard reset
  }
  out[id] = acc / 100.0f;
}

// ---------- fallback (round-4 structure, inline thresholds) ----------
__global__ __launch_bounds__(256, 4)
void snn_fallback(const float* __restrict__ x, const float* __restrict__ W,
                  float* __restrict__ out) {
  __shared__ __align__(16) float Wp[25 * 3 * 32 * 4];
  __shared__ uint32_t keys[100][2];
  const int tid = threadIdx.x;
  for (int s = tid; s < 25 * 3 * 32 * 4; s += 256) {
    int c = s & 3, jl = (s >> 2) & 31, rest = s >> 7;
    int q = rest % 3, jj = rest / 3;
    int o = q * 4 + c, j = jl + 32 * jj;
    float w = 0.0f;
    if (o < 10 && j < 784) w = W[o * 784 + j];
    Wp[s] = w;
  }
  if (tid < 100)
    threefry_full(0u, 42u, 0u, (uint32_t)tid, keys[tid][0], keys[tid][1]);
  __syncthreads();

  const int row = blockIdx.x * 8 + (tid >> 5);
  const int hl = tid & 31;
  const uint32_t cntbase = (uint32_t)row * 784u + (uint32_t)hl;
  const float* xrow = x + (size_t)row * 784;
  float v[10], acc[10];
#pragma unroll
  for (int o = 0; o < 10; ++o) { v[o] = 0.0f; acc[o] = 0.0f; }
  const float4* wq = (const float4*)&Wp[(size_t)hl * 4];

  for (int t = 0; t < 100; ++t) {
    uint32_t k0 = __builtin_amdgcn_readfirstlane(keys[t][0]);
    uint32_t k1 = __builtin_amdgcn_readfirstlane(keys[t][1]);
    uint32_t ks2 = k0 ^ k1 ^ 0x1BD11BDAu;
    float I[10];
#pragma unroll
    for (int o = 0; o < 10; ++o) I[o] = 0.0f;
#pragma unroll 5
    for (int jj = 0; jj < 25; ++jj) {
      const uint32_t bits = tf_bits(k0, k1, ks2, cntbase + (uint32_t)(jj * 32));
      int j = hl + jj * 32;
      float xv = xrow[(j < 784) ? j : 783];
      uint32_t k = (uint32_t)(xv * 8388608.0f);
      uint32_t thr = (j < 784) ? (k << 9) : 0u;
      const float s = (bits < thr) ? 1.0f : 0.0f;
      const float4 wa = wq[jj * 96];
      const float4 wb = wq[jj * 96 + 32];
      const float4 wc = wq[jj * 96 + 64];
      I[0] += s * wa.x; I[1] += s * wa.y; I[2] += s * wa.z; I[3] += s * wa.w;
      I[4] += s * wb.x; I[5] += s * wb.y; I[6] += s * wb.z; I[7] += s * wb.w;
      I[8] += s * wc.x; I[9] += s * wc.y;
    }
#pragma unroll
    for (int o = 0; o < 10; ++o) {
      float r = I[o];
#pragma unroll
      for (int m = 1; m < 32; m <<= 1) r += __shfl_xor(r, m, 32);
      I[o] = r;
    }
#pragma unroll
    for (int o = 0; o < 10; ++o) {
      float vv = v[o] + (I[o] - v[o]) * 0.5f;
      float s = (vv >= 1.0f) ? 1.0f : 0.0f;
      acc[o] += s;
      v[o] = (1.0f - s) * vv;
    }
  }
  if (hl == 0) {
#pragma unroll
    for (int o = 0; o < 10; ++o)
      out[(size_t)row * 10 + o] = acc[o] / 100.0f;
  }
}

extern "C" void kernel_launch(void* const* d_in, const int* in_sizes, int n_in,
                              void* d_out, int out_size, void* d_ws, size_t ws_size,
                              hipStream_t stream) {
  const float* x = (const float*)d_in[0];   // [16384,1,28,28] fp32
  const float* W = (const float*)d_in[1];   // [10,784] fp32
  float* out = (float*)d_out;               // [16384,10] fp32

  const size_t needI = (size_t)16384 * 100 * 10 * sizeof(float);   // 65.5 MB
  const size_t needT = (size_t)16384 * 784 * sizeof(uint32_t);     // 51.4 MB

  if (ws_size >= needI + needT) {
    float* Iws = (float*)d_ws;
    uint32_t* thr = (uint32_t*)((char*)d_ws + needI);
    hipLaunchKernelGGL(prep_thr, dim3((16384 * 784 + 255) / 256), dim3(256), 0,
                       stream, x, thr);
    hipLaunchKernelGGL((snn_phase1<true>), dim3(6400), dim3(256), 0, stream,
                       x, thr, W, Iws);
    hipLaunchKernelGGL(snn_phase3, dim3(640), dim3(256), 0, stream, Iws, out);
  } else if (ws_size >= needI) {
    float* Iws = (float*)d_ws;
    hipLaunchKernelGGL((snn_phase1<false>), dim3(6400), dim3(256), 0, stream,
                       x, (const uint32_t*)nullptr, W, Iws);
    hipLaunchKernelGGL(snn_phase3, dim3(640), dim3(256), 0, stream, Iws, out);
  } else {
    hipLaunchKernelGGL(snn_fallback, dim3(2048), dim3(256), 0, stream, x, W, out);
  }
}

// Round 8
// 3173.102 us; speedup vs baseline: 2.0054x; 1.0111x over previous
//
#include <hip/hip_runtime.h>
#include <stdint.h>

#define ROT(x, r) __builtin_rotateleft32((uint32_t)(x), (r))

// Threefry-2x32, 20 rounds
#define TF_G1(x0, x1) \
  x0 += x1; x1 = ROT(x1, 13); x1 ^= x0; \
  x0 += x1; x1 = ROT(x1, 15); x1 ^= x0; \
  x0 += x1; x1 = ROT(x1, 26); x1 ^= x0; \
  x0 += x1; x1 = ROT(x1, 6);  x1 ^= x0;

#define TF_G2(x0, x1) \
  x0 += x1; x1 = ROT(x1, 17); x1 ^= x0; \
  x0 += x1; x1 = ROT(x1, 29); x1 ^= x0; \
  x0 += x1; x1 = ROT(x1, 16); x1 ^= x0; \
  x0 += x1; x1 = ROT(x1, 24); x1 ^= x0;

__device__ __forceinline__ void threefry_full(uint32_t k0, uint32_t k1,
                                              uint32_t c0, uint32_t c1,
                                              uint32_t& o0, uint32_t& o1) {
  uint32_t ks2 = k0 ^ k1 ^ 0x1BD11BDAu;
  uint32_t x0 = c0 + k0, x1 = c1 + k1;
  TF_G1(x0, x1); x0 += k1;  x1 += ks2 + 1u;
  TF_G2(x0, x1); x0 += ks2; x1 += k0 + 2u;
  TF_G1(x0, x1); x0 += k0;  x1 += k1 + 3u;
  TF_G2(x0, x1); x0 += k1;  x1 += ks2 + 4u;
  TF_G1(x0, x1); x0 += ks2; x1 += k0 + 5u;
  o0 = x0; o1 = x1;
}

__device__ __forceinline__ uint32_t tf_bits(uint32_t k0, uint32_t k1, uint32_t ks2,
                                            uint32_t cnt) {
  uint32_t x0 = k0, x1 = cnt + k1;
  TF_G1(x0, x1); x0 += k1;  x1 += ks2 + 1u;
  TF_G2(x0, x1); x0 += ks2; x1 += k0 + 2u;
  TF_G1(x0, x1); x0 += k0;  x1 += k1 + 3u;
  TF_G2(x0, x1); x0 += k1;  x1 += ks2 + 4u;
  TF_G1(x0, x1); x0 += ks2; x1 += k0 + 5u;
  return x0 ^ x1;
}

// ---- 4-stream interleaved threefry (ILP=4 inside one thread) ----
#define SR4(r) \
  a0 += a1; a1 = ROT(a1, r); a1 ^= a0; \
  b0 += b1; b1 = ROT(b1, r); b1 ^= b0; \
  c0 += c1; c1 = ROT(c1, r); c1 ^= c0; \
  d0 += d1; d1 = ROT(d1, r); d1 ^= d0;

#define INJ4(p, q) \
  a0 += (p); a1 += (q); \
  b0 += (p); b1 += (q); \
  c0 += (p); c1 += (q); \
  d0 += (p); d1 += (q);

__device__ __forceinline__ void tf_bits4(uint32_t k0, uint32_t k1, uint32_t ks2,
                                         uint32_t ca, uint32_t cb, uint32_t cc,
                                         uint32_t cd, uint32_t& ra, uint32_t& rb,
                                         uint32_t& rc, uint32_t& rd) {
  uint32_t a0 = k0, a1 = ca + k1;
  uint32_t b0 = k0, b1 = cb + k1;
  uint32_t c0 = k0, c1 = cc + k1;
  uint32_t d0 = k0, d1 = cd + k1;
  SR4(13) SR4(15) SR4(26) SR4(6)
  INJ4(k1, ks2 + 1u)
  SR4(17) SR4(29) SR4(16) SR4(24)
  INJ4(ks2, k0 + 2u)
  SR4(13) SR4(15) SR4(26) SR4(6)
  INJ4(k0, k1 + 3u)
  SR4(17) SR4(29) SR4(16) SR4(24)
  INJ4(k1, ks2 + 4u)
  SR4(13) SR4(15) SR4(26) SR4(6)
  INJ4(ks2, k0 + 5u)
  ra = a0 ^ a1; rb = b0 ^ b1; rc = c0 ^ c1; rd = d0 ^ d1;
}

// thr[row*784+j] = floor(x*2^23)<<9 ;  bits < thr  ==  (u < x) bit-exactly
__global__ __launch_bounds__(256)
void prep_thr(const float* __restrict__ x, uint32_t* __restrict__ thr) {
  int i = blockIdx.x * 256 + threadIdx.x;
  if (i >= 16384 * 784) return;
  thr[i] = ((uint32_t)(x[i] * 8388608.0f)) << 9;   // exact: x = m*2^-23
}

// WT[j][0..15]: W[o][j] for o<10, pad 0 — 64 B/row so s_load_dwordx16 fits one row
__global__ __launch_bounds__(256)
void prep_wt(const float* __restrict__ W, float* __restrict__ WT) {
  int i = blockIdx.x * 256 + threadIdx.x;
  if (i >= 784 * 16) return;
  int j = i >> 4, o = i & 15;
  WT[i] = (o < 10) ? W[o * 784 + j] : 0.0f;
}

// ---------- phase 1: one thread = one (row,t); I[row,t,0..9] -> ws ----------
// ZERO LDS -> 8 waves/SIMD. j is wave-uniform -> W comes via scalar loads
// (s_load of WT row, SALU pipe). Thresholds: one uint4 vector load / 4 draws.
template <bool USE_THR>
__global__ __launch_bounds__(256, 8)
void snn_phase1(const float* __restrict__ x, const uint32_t* __restrict__ thrg,
                const float* __restrict__ WT, float* __restrict__ Iws) {
  const uint32_t task = blockIdx.x * 256u + (uint32_t)threadIdx.x;  // < 1,638,400
  const uint32_t row = task / 100u;
  const uint32_t t = task - row * 100u;

  // per-thread step key (73 ops amortized over 784 draws)
  uint32_t k0, k1;
  threefry_full(0u, 42u, 0u, t, k0, k1);
  const uint32_t ks2 = k0 ^ k1 ^ 0x1BD11BDAu;
  const uint32_t cnt0 = row * 784u;

  const uint32_t* trow = thrg + cnt0;            // 16B-aligned (3136 B stride)
  const float* xrow = x + cnt0;

  float I0 = 0, I1 = 0, I2 = 0, I3 = 0, I4 = 0,
        I5 = 0, I6 = 0, I7 = 0, I8 = 0, I9 = 0;

  for (uint32_t j = 0; j < 784u; j += 4u) {
    // ---- thresholds for this group (1 vector load / 4 draws) ----
    uint4 tv;
    if (USE_THR) {
      tv = *(const uint4*)(trow + j);
    } else {
      const float4 xv = *(const float4*)(xrow + j);
      tv.x = ((uint32_t)(xv.x * 8388608.0f)) << 9;
      tv.y = ((uint32_t)(xv.y * 8388608.0f)) << 9;
      tv.z = ((uint32_t)(xv.z * 8388608.0f)) << 9;
      tv.w = ((uint32_t)(xv.w * 8388608.0f)) << 9;
    }

    // ---- W rows for this group: j is uniform -> scalar loads (SGPRs) ----
    const float* w0 = WT + (size_t)(j + 0) * 16;
    const float* w1 = WT + (size_t)(j + 1) * 16;
    const float* w2 = WT + (size_t)(j + 2) * 16;
    const float* w3 = WT + (size_t)(j + 3) * 16;

    // ---- cipher (292 VALU ops, ILP 4) ----
    uint32_t ba, bb, bc, bd;
    tf_bits4(k0, k1, ks2, cnt0 + j, cnt0 + j + 1u, cnt0 + j + 2u, cnt0 + j + 3u,
             ba, bb, bc, bd);

    const float sa = (ba < tv.x) ? 1.0f : 0.0f;
    const float sb = (bb < tv.y) ? 1.0f : 0.0f;
    const float sc = (bc < tv.z) ? 1.0f : 0.0f;
    const float sd = (bd < tv.w) ? 1.0f : 0.0f;

    // j-ascending accumulation, per-accumulator order identical to rounds 6/7
    I0 += sa * w0[0]; I1 += sa * w0[1]; I2 += sa * w0[2]; I3 += sa * w0[3];
    I4 += sa * w0[4]; I5 += sa * w0[5]; I6 += sa * w0[6]; I7 += sa * w0[7];
    I8 += sa * w0[8]; I9 += sa * w0[9];

    I0 += sb * w1[0]; I1 += sb * w1[1]; I2 += sb * w1[2]; I3 += sb * w1[3];
    I4 += sb * w1[4]; I5 += sb * w1[5]; I6 += sb * w1[6]; I7 += sb * w1[7];
    I8 += sb * w1[8]; I9 += sb * w1[9];

    I0 += sc * w2[0]; I1 += sc * w2[1]; I2 += sc * w2[2]; I3 += sc * w2[3];
    I4 += sc * w2[4]; I5 += sc * w2[5]; I6 += sc * w2[6]; I7 += sc * w2[7];
    I8 += sc * w2[8]; I9 += sc * w2[9];

    I0 += sd * w3[0]; I1 += sd * w3[1]; I2 += sd * w3[2]; I3 += sd * w3[3];
    I4 += sd * w3[4]; I5 += sd * w3[5]; I6 += sd * w3[6]; I7 += sd * w3[7];
    I8 += sd * w3[8]; I9 += sd * w3[9];
  }

  float* dst = Iws + (size_t)task * 10;
  ((float2*)dst)[0] = make_float2(I0, I1);
  ((float2*)dst)[1] = make_float2(I2, I3);
  ((float2*)dst)[2] = make_float2(I4, I5);
  ((float2*)dst)[3] = make_float2(I6, I7);
  ((float2*)dst)[4] = make_float2(I8, I9);
}

// ---------- phase 3: one thread = one (row,o); LIF scan over t ----------
__global__ __launch_bounds__(256)
void snn_phase3(const float* __restrict__ Iws, float* __restrict__ out) {
  const uint32_t id = blockIdx.x * 256u + threadIdx.x;   // < 163,840
  const uint32_t row = id / 10u;
  const uint32_t o = id - row * 10u;
  const float* Ip = Iws + (size_t)row * 1000 + o;
  float v = 0.0f, acc = 0.0f;
  for (int t = 0; t < 100; ++t) {
    const float I = Ip[t * 10];
    const float vv = v + (I - v) * 0.5f;          // exact (x0.5)
    const float s = (vv >= 1.0f) ? 1.0f : 0.0f;
    acc += s;
    v = (1.0f - s) * vv;                          // hard reset
  }
  out[id] = acc / 100.0f;
}

// ---------- fallback (round-4 structure, inline thresholds) ----------
__global__ __launch_bounds__(256, 4)
void snn_fallback(const float* __restrict__ x, const float* __restrict__ W,
                  float* __restrict__ out) {
  __shared__ __align__(16) float Wp[25 * 3 * 32 * 4];
  __shared__ uint32_t keys[100][2];
  const int tid = threadIdx.x;
  for (int s = tid; s < 25 * 3 * 32 * 4; s += 256) {
    int c = s & 3, jl = (s >> 2) & 31, rest = s >> 7;
    int q = rest % 3, jj = rest / 3;
    int o = q * 4 + c, j = jl + 32 * jj;
    float w = 0.0f;
    if (o < 10 && j < 784) w = W[o * 784 + j];
    Wp[s] = w;
  }
  if (tid < 100)
    threefry_full(0u, 42u, 0u, (uint32_t)tid, keys[tid][0], keys[tid][1]);
  __syncthreads();

  const int row = blockIdx.x * 8 + (tid >> 5);
  const int hl = tid & 31;
  const uint32_t cntbase = (uint32_t)row * 784u + (uint32_t)hl;
  const float* xrow = x + (size_t)row * 784;
  float v[10], acc[10];
#pragma unroll
  for (int o = 0; o < 10; ++o) { v[o] = 0.0f; acc[o] = 0.0f; }
  const float4* wq = (const float4*)&Wp[(size_t)hl * 4];

  for (int t = 0; t < 100; ++t) {
    uint32_t k0 = __builtin_amdgcn_readfirstlane(keys[t][0]);
    uint32_t k1 = __builtin_amdgcn_readfirstlane(keys[t][1]);
    uint32_t ks2 = k0 ^ k1 ^ 0x1BD11BDAu;
    float I[10];
#pragma unroll
    for (int o = 0; o < 10; ++o) I[o] = 0.0f;
#pragma unroll 5
    for (int jj = 0; jj < 25; ++jj) {
      const uint32_t bits = tf_bits(k0, k1, ks2, cntbase + (uint32_t)(jj * 32));
      int j = hl + jj * 32;
      float xv = xrow[(j < 784) ? j : 783];
      uint32_t k = (uint32_t)(xv * 8388608.0f);
      uint32_t thr = (j < 784) ? (k << 9) : 0u;
      const float s = (bits < thr) ? 1.0f : 0.0f;
      const float4 wa = wq[jj * 96];
      const float4 wb = wq[jj * 96 + 32];
      const float4 wc = wq[jj * 96 + 64];
      I[0] += s * wa.x; I[1] += s * wa.y; I[2] += s * wa.z; I[3] += s * wa.w;
      I[4] += s * wb.x; I[5] += s * wb.y; I[6] += s * wb.z; I[7] += s * wb.w;
      I[8] += s * wc.x; I[9] += s * wc.y;
    }
#pragma unroll
    for (int o = 0; o < 10; ++o) {
      float r = I[o];
#pragma unroll
      for (int m = 1; m < 32; m <<= 1) r += __shfl_xor(r, m, 32);
      I[o] = r;
    }
#pragma unroll
    for (int o = 0; o < 10; ++o) {
      float vv = v[o] + (I[o] - v[o]) * 0.5f;
      float s = (vv >= 1.0f) ? 1.0f : 0.0f;
      acc[o] += s;
      v[o] = (1.0f - s) * vv;
    }
  }
  if (hl == 0) {
#pragma unroll
    for (int o = 0; o < 10; ++o)
      out[(size_t)row * 10 + o] = acc[o] / 100.0f;
  }
}

extern "C" void kernel_launch(void* const* d_in, const int* in_sizes, int n_in,
                              void* d_out, int out_size, void* d_ws, size_t ws_size,
                              hipStream_t stream) {
  const float* x = (const float*)d_in[0];   // [16384,1,28,28] fp32
  const float* W = (const float*)d_in[1];   // [10,784] fp32
  float* out = (float*)d_out;               // [16384,10] fp32

  const size_t needI = (size_t)16384 * 100 * 10 * sizeof(float);   // 65.5 MB
  const size_t needW = (size_t)784 * 16 * sizeof(float);           // 50 KB
  const size_t needT = (size_t)16384 * 784 * sizeof(uint32_t);     // 51.4 MB

  if (ws_size >= needI + needW) {
    float* Iws = (float*)d_ws;
    float* WT = (float*)((char*)d_ws + needI);
    hipLaunchKernelGGL(prep_wt, dim3((784 * 16 + 255) / 256), dim3(256), 0,
                       stream, W, WT);
    if (ws_size >= needI + needW + needT) {
      uint32_t* thr = (uint32_t*)((char*)d_ws + needI + needW);
      hipLaunchKernelGGL(prep_thr, dim3((16384 * 784 + 255) / 256), dim3(256), 0,
                         stream, x, thr);
      hipLaunchKernelGGL((snn_phase1<true>), dim3(6400), dim3(256), 0, stream,
                         x, thr, WT, Iws);
    } else {
      hipLaunchKernelGGL((snn_phase1<false>), dim3(6400), dim3(256), 0, stream,
                         x, (const uint32_t*)nullptr, WT, Iws);
    }
    hipLaunchKernelGGL(snn_phase3, dim3(640), dim3(256), 0, stream, Iws, out);
  } else {
    hipLaunchKernelGGL(snn_fallback, dim3(2048), dim3(256), 0, stream, x, W, out);
  }
}